// Round 10
// baseline (113.063 us; speedup 1.0000x reference)
//
#include <hip/hip_runtime.h>

// Fused: bicubic 2x upsample -> leaky_relu(0.01) -> antialiased bicubic 2x down.
// NHWC f32, B=16, H=W=128, C=128.
// Round 10 = round 9 (packed-fp16 horizontal pipeline, fp16x2 LDS exchange,
// lgkm-only barriers, no launch-bounds min-waves) with RS=8 / 2048 blocks:
// 21.5KB LDS -> 7 blocks/CU resident, ~28 waves/CU (was 16) for latency hiding.

typedef _Float16 h2 __attribute__((ext_vector_type(2)));

#define HH 128
#define WW 128
#define CC 128
#define RS 8        // output rows per strip
#define CH 16       // channels per block
#define PADH2 132   // LDS row stride in h2 elems (16B-aligned quads)
#define NSTEP (RS + 4)

// lgkm-only barrier: LDS visibility without draining global loads/stores.
#define LBAR() asm volatile("s_waitcnt lgkmcnt(0)\n\ts_barrier" ::: "memory")

__device__ __forceinline__ h2 H2(float v) {
  _Float16 h = (_Float16)v;
  return (h2){h, h};
}

__device__ __forceinline__ double keys_cubic(double x) {
  // JAX _fill_keys_cubic_kernel (a = -0.5)
  if (x >= 2.0) return 0.0;
  if (x >= 1.0) return ((-0.5 * x + 2.5) * x - 4.0) * x + 2.0;
  return (1.5 * x - 2.5) * x * x + 1.0;
}

__global__ __launch_bounds__(256) void fused_updown_kernel(
    const float* __restrict__ x, float* __restrict__ out) {
  __shared__ __align__(16) float wUpV[256][4];     // fine row -> 4 taps (f32, v-up)
  __shared__ __align__(16) float wDnE[4][8];       // out row/col 0,1,126,127 -> 8 taps
  __shared__ __align__(16) h2 wUpH2[6][4];         // fine col 0,1,2,253,254,255 (splat)
  __shared__ __align__(16) h2 wDnH2[4][8];         // out col 0,1,126,127 (splat)
  __shared__ __align__(16) h2 rowv[2][CH][PADH2];  // packed (even,odd) fine rows, fp16

  const int tid = threadIdx.x;

  // ---- weight tables (renormalized truncation, matches jax.image.resize) ----
  {
    const int k = tid;
    const double q = 0.5 * k - 0.25;          // sample_f = (k+0.5)/2 - 0.5
    const int st = ((k + 1) >> 1) - 2;
    double wr[4], s = 0.0;
#pragma unroll
    for (int i = 0; i < 4; ++i) {
      const int col = st + i;
      double w = (col >= 0 && col <= 127) ? keys_cubic(fabs((double)col - q)) : 0.0;
      wr[i] = w; s += w;
    }
    const double inv = 1.0 / s;
#pragma unroll
    for (int i = 0; i < 4; ++i) wUpV[k][i] = (float)(wr[i] * inv);
  }
  if (tid < 4) {
    const int e = tid;
    const int j = (e < 2) ? e : 124 + e;      // 0,1,126,127
    const double p = 2.0 * j + 0.5;           // sample_f = (j+0.5)*2 - 0.5
    const int st = 2 * j - 3;
    double wr[8], s = 0.0;
#pragma unroll
    for (int i = 0; i < 8; ++i) {
      const int col = st + i;
      double w = (col >= 0 && col <= 255) ? keys_cubic(0.5 * fabs((double)col - p)) : 0.0;
      wr[i] = w; s += w;
    }
    const double inv = 1.0 / s;
#pragma unroll
    for (int i = 0; i < 8; ++i) wDnE[e][i] = (float)(wr[i] * inv);
  }
  __syncthreads();
  // fp16 splat copies of the boundary tables (visible after the loop's first LBAR)
  if (tid < 6) {
    const int k = (tid < 3) ? tid : 250 + tid;   // 0,1,2,253,254,255
#pragma unroll
    for (int i = 0; i < 4; ++i) wUpH2[tid][i] = H2(wUpV[k][i]);
  }
  if (tid < 4) {
#pragma unroll
    for (int i = 0; i < 8; ++i) wDnH2[tid][i] = H2(wDnE[tid][i]);
  }

  const int bid = blockIdx.x;
  const int b = bid & 15;
  const int strip = (bid >> 4) & 15;           // 0..15
  const int chunk = bid >> 8;                  // 0..7
  const int oy0 = strip * RS;
  const int c0 = chunk * CH;
  const int c = tid & 15;                      // channel (lane-contiguous)
  const int g = tid >> 4;                      // col group 0..15
  const int col0 = g * 8;
  const bool gL = (g == 0), gR = (g == 15);

  const float* xbase = x + (size_t)b * (HH * WW * CC) + (size_t)col0 * CC + (c0 + c);
  float* obase = out + (size_t)b * (HH * WW * CC) + (size_t)col0 * CC + (c0 + c);
  const int m0 = oy0 - 2;

  auto load_row = [&](float (&d)[8], int row) {
    row = row < 0 ? 0 : (row > 127 ? 127 : row);
    const float* p = xbase + (size_t)row * (WW * CC);
#pragma unroll
    for (int j = 0; j < 8; ++j) d[j] = p[j * CC];
  };

  // vertical-downsample weight for output row oy at tap (interior const cst)
  auto wdGet = [&](int oy, float cst, int tap) -> float {
    if (oy < 0 || oy > 127) return 0.f;
    if (oy < 2) return wDnE[oy][tap];
    if (oy > 125) return wDnE[oy - 124][tap];
    return cst;
  };

  float r0[8], r1[8], r2[8], r3[8], r4[8], r5[8];
  float A0[8], A1[8], A2[8], A3[8], A4[8];
#pragma unroll
  for (int i = 0; i < 8; ++i) { A0[i]=0.f; A1[i]=0.f; A2[i]=0.f; A3[i]=0.f; A4[i]=0.f; }

  load_row(r0, m0 - 2);
  load_row(r1, m0 - 1);
  load_row(r2, m0);
  load_row(r3, m0 + 1);
  load_row(r4, m0 + 2);
  load_row(r5, m0 + 3);

  for (int t = 0; t < NSTEP; ++t) {
    const int m = m0 + t;
    if (t > 0) {
#pragma unroll
      for (int i = 0; i < 8; ++i) {
        r0[i]=r1[i]; r1[i]=r2[i]; r2[i]=r3[i]; r3[i]=r4[i]; r4[i]=r5[i];
      }
      load_row(r5, m + 3);                 // consumed next step (spans the LBAR)
    }
    const bool mOK = (m >= 0) && (m <= 127);
    const int sp = t & 1;
    __align__(16) h2 vh[8];                 // packed (even,odd) own fine cols
    if (mOK) {
      // vertical upsample in f32 (even row 2m | odd row 2m+1), then pack fp16
      float4 we, wo;
      if (m >= 2 && m <= 125) {
        we = make_float4(-0.0234375f, 0.2265625f, 0.8671875f, -0.0703125f);
        wo = make_float4(-0.0703125f, 0.8671875f, 0.2265625f, -0.0234375f);
      } else {
        we = *(const float4*)wUpV[2 * m];
        wo = *(const float4*)wUpV[2 * m + 1];
      }
#pragma unroll
      for (int j = 0; j < 8; ++j) {
        const float vE = (we.x * r0[j] + we.y * r1[j]) + (we.z * r2[j] + we.w * r3[j]);
        const float vO = (wo.x * r1[j] + wo.y * r2[j]) + (wo.z * r3[j] + wo.w * r4[j]);
        vh[j] = (h2){(_Float16)vE, (_Float16)vO};
      }
      *(float4*)&rowv[sp][c][col0]     = *(const float4*)&vh[0];
      *(float4*)&rowv[sp][c][col0 + 4] = *(const float4*)&vh[4];
    }
    LBAR();
    if (mOK) {
      // halo gather: packed fine-row pair at coarse cols col0-4 .. col0+11
      __align__(16) h2 vv[16];
      if (!gL) {
        *(float4*)&vv[0] = *(const float4*)&rowv[sp][c][col0 - 4];
      } else {
#pragma unroll
        for (int i = 0; i < 4; ++i) vv[i] = H2(0.f);
      }
#pragma unroll
      for (int j = 0; j < 8; ++j) vv[4 + j] = vh[j];
      if (!gR) {
        *(float4*)&vv[12] = *(const float4*)&rowv[sp][c][col0 + 8];
      } else {
#pragma unroll
        for (int i = 0; i < 4; ++i) vv[12 + i] = H2(0.f);
      }

      // horizontal upsample + leaky (packed fp16), fine cols k0..k0+21
      h2 ff[22];
#pragma unroll
      for (int u = 0; u < 22; ++u) {
        const int s = (u >> 1) + 1;
        h2 t2;
        if (u & 1)
          t2 = (vv[s] * H2(-0.0234375f) + vv[s + 1] * H2(0.2265625f))
             + (vv[s + 2] * H2(0.8671875f) + vv[s + 3] * H2(-0.0703125f));
        else
          t2 = (vv[s] * H2(-0.0703125f) + vv[s + 1] * H2(0.8671875f))
             + (vv[s + 2] * H2(0.2265625f) + vv[s + 3] * H2(-0.0234375f));
        ff[u] = __builtin_elementwise_max(t2, t2 * H2(0.01f));
      }
      if (gL) {              // fine cols 0,1,2 boundary weights (k0 = -3)
#pragma unroll
        for (int u = 3; u <= 5; ++u) {
          const int s = (u >> 1) + 1;
          h2 t2 = (vv[s] * wUpH2[u - 3][0] + vv[s + 1] * wUpH2[u - 3][1])
                + (vv[s + 2] * wUpH2[u - 3][2] + vv[s + 3] * wUpH2[u - 3][3]);
          ff[u] = __builtin_elementwise_max(t2, t2 * H2(0.01f));
        }
      }
      if (gR) {              // fine cols 253,254,255 (k0 = 237)
#pragma unroll
        for (int u = 16; u <= 18; ++u) {
          const int s = (u >> 1) + 1;
          h2 t2 = (vv[s] * wUpH2[u - 13][0] + vv[s + 1] * wUpH2[u - 13][1])
                + (vv[s + 2] * wUpH2[u - 13][2] + vv[s + 3] * wUpH2[u - 13][3]);
          ff[u] = __builtin_elementwise_max(t2, t2 * H2(0.01f));
        }
      }

      // horizontal downsample (packed fp16, interior symmetric 8-tap)
      h2 tt[8];
#pragma unroll
      for (int jj = 0; jj < 8; ++jj) {
        const h2 p0 = ff[2*jj]     + ff[2*jj + 7];
        const h2 p1 = ff[2*jj + 1] + ff[2*jj + 6];
        const h2 p2 = ff[2*jj + 2] + ff[2*jj + 5];
        const h2 p3 = ff[2*jj + 3] + ff[2*jj + 4];
        tt[jj] = (p0 * H2(-0.01171875f) + p1 * H2(-0.03515625f))
               + (p2 * H2(0.11328125f)  + p3 * H2(0.43359375f));
      }
      if (gL) {
#pragma unroll
        for (int jj = 0; jj < 2; ++jj) {
          h2 s2 = H2(0.f);
#pragma unroll
          for (int i = 0; i < 8; ++i) s2 += ff[2*jj + i] * wDnH2[jj][i];
          tt[jj] = s2;
        }
      }
      if (gR) {
#pragma unroll
        for (int jj = 6; jj < 8; ++jj) {
          h2 s2 = H2(0.f);
#pragma unroll
          for (int i = 0; i < 8; ++i) s2 += ff[2*jj + i] * wDnH2[jj - 4][i];
          tt[jj] = s2;
        }
      }

      // vertical-downsample scatter in f32
      const float wE0 = wdGet(m - 2, -0.01171875f, 7);
      const float wE1 = wdGet(m - 1, 0.11328125f, 5);
      const float wE2 = wdGet(m, 0.43359375f, 3);
      const float wE3 = wdGet(m + 1, -0.03515625f, 1);
      const float wO0 = wdGet(m - 1, -0.03515625f, 6);
      const float wO1 = wdGet(m, 0.43359375f, 4);
      const float wO2 = wdGet(m + 1, 0.11328125f, 2);
      const float wO3 = wdGet(m + 2, -0.01171875f, 0);
#pragma unroll
      for (int jj = 0; jj < 8; ++jj) {
        const float te = (float)tt[jj].x, to = (float)tt[jj].y;
        A0[jj] = fmaf(wE0, te, A0[jj]);
        A1[jj] = fmaf(wE1, te, fmaf(wO0, to, A1[jj]));
        A2[jj] = fmaf(wE2, te, fmaf(wO1, to, A2[jj]));
        A3[jj] = fmaf(wE3, te, fmaf(wO2, to, A3[jj]));
        A4[jj] = fmaf(wO3, to, A4[jj]);
      }
    }
    if (m - 2 >= oy0) {
      float* op = obase + (size_t)(m - 2) * (WW * CC);
#pragma unroll
      for (int jj = 0; jj < 8; ++jj) op[jj * CC] = A0[jj];
    }
#pragma unroll
    for (int jj = 0; jj < 8; ++jj) {
      A0[jj]=A1[jj]; A1[jj]=A2[jj]; A2[jj]=A3[jj]; A3[jj]=A4[jj]; A4[jj]=0.f;
    }
  }
}

extern "C" void kernel_launch(void* const* d_in, const int* in_sizes, int n_in,
                              void* d_out, int out_size, void* d_ws, size_t ws_size,
                              hipStream_t stream) {
  const float* x = (const float*)d_in[0];
  float* o = (float*)d_out;
  dim3 grid(16 * 16 * 8);   // batch(16) x strips(16) x channel-chunks(8)
  dim3 block(256);
  hipLaunchKernelGGL(fused_updown_kernel, grid, block, 0, stream, x, o);
}

// Round 11
// 110.667 us; speedup vs baseline: 1.0217x; 1.0217x over previous
//
#include <hip/hip_runtime.h>

// Fused: bicubic 2x upsample -> leaky_relu(0.01) -> antialiased bicubic 2x down.
// NHWC f32, B=16, H=W=128, C=128.
// Round 11: BARRIER-FREE main loop. Each thread owns a 14-column coarse ring
// (own 8 cols + 3-col halo each side, redundantly computed) so the vertical-
// upsample halo exchange (LDS + barrier) disappears entirely. Horizontal
// pipeline stays packed fp16 (r9). LDS holds only weight tables (~5KB).
// 5-row ring; R4 loaded at step top, consumed by the odd-row v-up.

typedef _Float16 h2 __attribute__((ext_vector_type(2)));

#define HH 128
#define WW 128
#define CC 128
#define RS 16       // output rows per strip
#define CH 16       // channels per block
#define NC 14       // coarse cols per thread (8 own + 3 halo each side)
#define NSTEP (RS + 4)

__device__ __forceinline__ h2 H2(float v) {
  _Float16 h = (_Float16)v;
  return (h2){h, h};
}

__device__ __forceinline__ double keys_cubic(double x) {
  // JAX _fill_keys_cubic_kernel (a = -0.5)
  if (x >= 2.0) return 0.0;
  if (x >= 1.0) return ((-0.5 * x + 2.5) * x - 4.0) * x + 2.0;
  return (1.5 * x - 2.5) * x * x + 1.0;
}

__global__ __launch_bounds__(256) void fused_updown_kernel(
    const float* __restrict__ x, float* __restrict__ out) {
  __shared__ __align__(16) float wUpV[256][4];  // fine row -> 4 taps (f32, v-up)
  __shared__ __align__(16) float wDnE[4][8];    // out row 0,1,126,127 -> 8 taps
  __shared__ __align__(16) h2 wUpH2[6][4];      // fine col 0,1,2,253,254,255 (splat)
  __shared__ __align__(16) h2 wDnH2[4][8];      // out col 0,1,126,127 (splat)

  const int tid = threadIdx.x;

  // ---- weight tables (renormalized truncation, matches jax.image.resize) ----
  {
    const int k = tid;
    const double q = 0.5 * k - 0.25;          // sample_f = (k+0.5)/2 - 0.5
    const int st = ((k + 1) >> 1) - 2;
    double wr[4], s = 0.0;
#pragma unroll
    for (int i = 0; i < 4; ++i) {
      const int col = st + i;
      double w = (col >= 0 && col <= 127) ? keys_cubic(fabs((double)col - q)) : 0.0;
      wr[i] = w; s += w;
    }
    const double inv = 1.0 / s;
#pragma unroll
    for (int i = 0; i < 4; ++i) wUpV[k][i] = (float)(wr[i] * inv);
  }
  if (tid < 6) {   // fp16 splat boundary upsample weights (independent recompute)
    const int k = (tid < 3) ? tid : 250 + tid;   // 0,1,2,253,254,255
    const double q = 0.5 * k - 0.25;
    const int st = ((k + 1) >> 1) - 2;
    double wr[4], s = 0.0;
#pragma unroll
    for (int i = 0; i < 4; ++i) {
      const int col = st + i;
      double w = (col >= 0 && col <= 127) ? keys_cubic(fabs((double)col - q)) : 0.0;
      wr[i] = w; s += w;
    }
    const double inv = 1.0 / s;
#pragma unroll
    for (int i = 0; i < 4; ++i) wUpH2[tid][i] = H2((float)(wr[i] * inv));
  }
  if (tid < 4) {   // f32 + fp16 splat boundary downsample weights
    const int e = tid;
    const int j = (e < 2) ? e : 124 + e;      // 0,1,126,127
    const double p = 2.0 * j + 0.5;           // sample_f = (j+0.5)*2 - 0.5
    const int st = 2 * j - 3;
    double wr[8], s = 0.0;
#pragma unroll
    for (int i = 0; i < 8; ++i) {
      const int col = st + i;
      double w = (col >= 0 && col <= 255) ? keys_cubic(0.5 * fabs((double)col - p)) : 0.0;
      wr[i] = w; s += w;
    }
    const double inv = 1.0 / s;
#pragma unroll
    for (int i = 0; i < 8; ++i) {
      const float wf = (float)(wr[i] * inv);
      wDnE[e][i] = wf;
      wDnH2[e][i] = H2(wf);
    }
  }
  __syncthreads();   // the ONLY barrier in the kernel

  const int bid = blockIdx.x;
  const int b = bid & 15;
  const int strip = (bid >> 4) & 7;
  const int chunk = bid >> 7;                  // 0..7
  const int oy0 = strip * RS;
  const int c0 = chunk * CH;
  const int c = tid & 15;                      // channel (lane-contiguous)
  const int g = tid >> 4;                      // col group 0..15
  const int col0 = g * 8;
  const bool gL = (g == 0), gR = (g == 15);

  // loop-invariant clamped column offsets (element units)
  int co[NC];
#pragma unroll
  for (int i = 0; i < NC; ++i) {
    int cl = col0 - 3 + i;
    cl = cl < 0 ? 0 : (cl > 127 ? 127 : cl);
    co[i] = cl * CC;
  }
  const float* xb = x + (size_t)b * (HH * WW * CC) + (c0 + c);
  float* obase = out + (size_t)b * (HH * WW * CC) + (size_t)col0 * CC + (c0 + c);
  const int m0 = oy0 - 2;

  auto ldrow = [&](float (&d)[NC], int row) {
    row = row < 0 ? 0 : (row > 127 ? 127 : row);
    const float* p = xb + (size_t)row * (WW * CC);
#pragma unroll
    for (int i = 0; i < NC; ++i) d[i] = p[co[i]];
  };

  // vertical-downsample weight for output row oy at tap (interior const cst)
  auto wdGet = [&](int oy, float cst, int tap) -> float {
    if (oy < 0 || oy > 127) return 0.f;
    if (oy < 2) return wDnE[oy][tap];
    if (oy > 125) return wDnE[oy - 124][tap];
    return cst;
  };

  float R0[NC], R1[NC], R2[NC], R3[NC], R4[NC];
  float A0[8], A1[8], A2[8], A3[8], A4[8];
#pragma unroll
  for (int i = 0; i < 8; ++i) { A0[i]=0.f; A1[i]=0.f; A2[i]=0.f; A3[i]=0.f; A4[i]=0.f; }

  ldrow(R0, m0 - 2);
  ldrow(R1, m0 - 1);
  ldrow(R2, m0);
  ldrow(R3, m0 + 1);

  for (int t = 0; t < NSTEP; ++t) {
    const int m = m0 + t;
    if (t > 0) {
#pragma unroll
      for (int i = 0; i < NC; ++i) { R0[i]=R1[i]; R1[i]=R2[i]; R2[i]=R3[i]; R3[i]=R4[i]; }
    }
    ldrow(R4, m + 2);                        // consumed by the odd-row v-up below
    const bool mOK = (m >= 0) && (m <= 127);
    if (mOK) {
      // vertical upsample over 14 cols (own + halo), f32, then pack fp16
      float4 we, wo;
      if (m >= 2 && m <= 125) {
        we = make_float4(-0.0234375f, 0.2265625f, 0.8671875f, -0.0703125f);
        wo = make_float4(-0.0703125f, 0.8671875f, 0.2265625f, -0.0234375f);
      } else {
        we = *(const float4*)wUpV[2 * m];
        wo = *(const float4*)wUpV[2 * m + 1];
      }
      h2 vvn[NC];                            // vvn[i] = coarse col col0-3+i, (even,odd)
#pragma unroll
      for (int i = 0; i < NC; ++i) {
        const float vE = (we.x * R0[i] + we.y * R1[i]) + (we.z * R2[i] + we.w * R3[i]);
        const float vO = (wo.x * R1[i] + wo.y * R2[i]) + (wo.z * R3[i] + wo.w * R4[i]);
        vvn[i] = (h2){(_Float16)vE, (_Float16)vO};
      }

      // horizontal upsample + leaky (packed fp16), fine cols k0..k0+21
      h2 ff[22];
#pragma unroll
      for (int u = 0; u < 22; ++u) {
        const int s = u >> 1;                // vvn index base (shifted vs r9)
        h2 t2;
        if (u & 1)
          t2 = (vvn[s] * H2(-0.0234375f) + vvn[s + 1] * H2(0.2265625f))
             + (vvn[s + 2] * H2(0.8671875f) + vvn[s + 3] * H2(-0.0703125f));
        else
          t2 = (vvn[s] * H2(-0.0703125f) + vvn[s + 1] * H2(0.8671875f))
             + (vvn[s + 2] * H2(0.2265625f) + vvn[s + 3] * H2(-0.0234375f));
        ff[u] = __builtin_elementwise_max(t2, t2 * H2(0.01f));
      }
      if (gL) {              // fine cols 0,1,2 boundary weights (k0 = -3)
#pragma unroll
        for (int u = 3; u <= 5; ++u) {
          const int s = u >> 1;
          h2 t2 = (vvn[s] * wUpH2[u - 3][0] + vvn[s + 1] * wUpH2[u - 3][1])
                + (vvn[s + 2] * wUpH2[u - 3][2] + vvn[s + 3] * wUpH2[u - 3][3]);
          ff[u] = __builtin_elementwise_max(t2, t2 * H2(0.01f));
        }
      }
      if (gR) {              // fine cols 253,254,255 (k0 = 237)
#pragma unroll
        for (int u = 16; u <= 18; ++u) {
          const int s = u >> 1;
          h2 t2 = (vvn[s] * wUpH2[u - 13][0] + vvn[s + 1] * wUpH2[u - 13][1])
                + (vvn[s + 2] * wUpH2[u - 13][2] + vvn[s + 3] * wUpH2[u - 13][3]);
          ff[u] = __builtin_elementwise_max(t2, t2 * H2(0.01f));
        }
      }

      // horizontal downsample (packed fp16, interior symmetric 8-tap)
      h2 tt[8];
#pragma unroll
      for (int jj = 0; jj < 8; ++jj) {
        const h2 p0 = ff[2*jj]     + ff[2*jj + 7];
        const h2 p1 = ff[2*jj + 1] + ff[2*jj + 6];
        const h2 p2 = ff[2*jj + 2] + ff[2*jj + 5];
        const h2 p3 = ff[2*jj + 3] + ff[2*jj + 4];
        tt[jj] = (p0 * H2(-0.01171875f) + p1 * H2(-0.03515625f))
               + (p2 * H2(0.11328125f)  + p3 * H2(0.43359375f));
      }
      if (gL) {
#pragma unroll
        for (int jj = 0; jj < 2; ++jj) {
          h2 s2 = H2(0.f);
#pragma unroll
          for (int i = 0; i < 8; ++i) s2 += ff[2*jj + i] * wDnH2[jj][i];
          tt[jj] = s2;
        }
      }
      if (gR) {
#pragma unroll
        for (int jj = 6; jj < 8; ++jj) {
          h2 s2 = H2(0.f);
#pragma unroll
          for (int i = 0; i < 8; ++i) s2 += ff[2*jj + i] * wDnH2[jj - 4][i];
          tt[jj] = s2;
        }
      }

      // vertical-downsample scatter in f32
      const float wE0 = wdGet(m - 2, -0.01171875f, 7);
      const float wE1 = wdGet(m - 1, 0.11328125f, 5);
      const float wE2 = wdGet(m, 0.43359375f, 3);
      const float wE3 = wdGet(m + 1, -0.03515625f, 1);
      const float wO0 = wdGet(m - 1, -0.03515625f, 6);
      const float wO1 = wdGet(m, 0.43359375f, 4);
      const float wO2 = wdGet(m + 1, 0.11328125f, 2);
      const float wO3 = wdGet(m + 2, -0.01171875f, 0);
#pragma unroll
      for (int jj = 0; jj < 8; ++jj) {
        const float te = (float)tt[jj].x, to = (float)tt[jj].y;
        A0[jj] = fmaf(wE0, te, A0[jj]);
        A1[jj] = fmaf(wE1, te, fmaf(wO0, to, A1[jj]));
        A2[jj] = fmaf(wE2, te, fmaf(wO1, to, A2[jj]));
        A3[jj] = fmaf(wE3, te, fmaf(wO2, to, A3[jj]));
        A4[jj] = fmaf(wO3, to, A4[jj]);
      }
    }
    if (m - 2 >= oy0) {
      float* op = obase + (size_t)(m - 2) * (WW * CC);
#pragma unroll
      for (int jj = 0; jj < 8; ++jj) op[jj * CC] = A0[jj];
    }
#pragma unroll
    for (int jj = 0; jj < 8; ++jj) {
      A0[jj]=A1[jj]; A1[jj]=A2[jj]; A2[jj]=A3[jj]; A3[jj]=A4[jj]; A4[jj]=0.f;
    }
  }
}

extern "C" void kernel_launch(void* const* d_in, const int* in_sizes, int n_in,
                              void* d_out, int out_size, void* d_ws, size_t ws_size,
                              hipStream_t stream) {
  const float* x = (const float*)d_in[0];
  float* o = (float*)d_out;
  dim3 grid(16 * 8 * 8);   // batch(16) x strips(8) x channel-chunks(8)
  dim3 block(256);
  hipLaunchKernelGGL(fused_updown_kernel, grid, block, 0, stream, x, o);
}

// Round 12
// 96.022 us; speedup vs baseline: 1.1775x; 1.1525x over previous
//
#include <hip/hip_runtime.h>

// Fused: bicubic 2x upsample -> leaky_relu(0.01) -> antialiased bicubic 2x down.
// NHWC f32, B=16, H=W=128, C=128.
// Round 12 = round 9 (packed-fp16 horizontal pipeline, fp16 LDS exchange,
// lgkm-only barrier, RS=16/1024 blocks) +
//  - 5-step unrolled register renaming (zero ring-rotation movs)
//  - v_dot2_f32_f16 vertical-downsample with constant fp16 weight pairs on
//    interior steps (weights are dyadic /256 -> fp16-exact; boundary steps
//    keep the f32 path).

typedef _Float16 h2 __attribute__((ext_vector_type(2)));

#define HH 128
#define WW 128
#define CC 128
#define RS 16       // output rows per strip
#define CH 16       // channels per block
#define PADH2 132   // LDS row stride in h2 elems (16B-aligned quads)
#define NSTEP (RS + 4)

// lgkm-only barrier: LDS visibility without draining global loads/stores.
#define LBAR() asm volatile("s_waitcnt lgkmcnt(0)\n\ts_barrier" ::: "memory")

__device__ __forceinline__ h2 H2(float v) {
  _Float16 h = (_Float16)v;
  return (h2){h, h};
}

__device__ __forceinline__ double keys_cubic(double x) {
  // JAX _fill_keys_cubic_kernel (a = -0.5)
  if (x >= 2.0) return 0.0;
  if (x >= 1.0) return ((-0.5 * x + 2.5) * x - 4.0) * x + 2.0;
  return (1.5 * x - 2.5) * x * x + 1.0;
}

__global__ __launch_bounds__(256) void fused_updown_kernel(
    const float* __restrict__ x, float* __restrict__ out) {
  __shared__ __align__(16) float wUpV[256][4];     // fine row -> 4 taps (f32, v-up)
  __shared__ __align__(16) float wDnE[4][8];       // out row/col 0,1,126,127 -> 8 taps
  __shared__ __align__(16) h2 wUpH2[6][4];         // fine col 0,1,2,253,254,255 (splat)
  __shared__ __align__(16) h2 wDnH2[4][8];         // out col 0,1,126,127 (splat)
  __shared__ __align__(16) h2 rowv[2][CH][PADH2];  // packed (even,odd) fine rows, fp16

  const int tid = threadIdx.x;

  // ---- weight tables (renormalized truncation, matches jax.image.resize) ----
  {
    const int k = tid;
    const double q = 0.5 * k - 0.25;          // sample_f = (k+0.5)/2 - 0.5
    const int st = ((k + 1) >> 1) - 2;
    double wr[4], s = 0.0;
#pragma unroll
    for (int i = 0; i < 4; ++i) {
      const int col = st + i;
      double w = (col >= 0 && col <= 127) ? keys_cubic(fabs((double)col - q)) : 0.0;
      wr[i] = w; s += w;
    }
    const double inv = 1.0 / s;
#pragma unroll
    for (int i = 0; i < 4; ++i) wUpV[k][i] = (float)(wr[i] * inv);
  }
  if (tid < 4) {
    const int e = tid;
    const int j = (e < 2) ? e : 124 + e;      // 0,1,126,127
    const double p = 2.0 * j + 0.5;           // sample_f = (j+0.5)*2 - 0.5
    const int st = 2 * j - 3;
    double wr[8], s = 0.0;
#pragma unroll
    for (int i = 0; i < 8; ++i) {
      const int col = st + i;
      double w = (col >= 0 && col <= 255) ? keys_cubic(0.5 * fabs((double)col - p)) : 0.0;
      wr[i] = w; s += w;
    }
    const double inv = 1.0 / s;
#pragma unroll
    for (int i = 0; i < 8; ++i) wDnE[e][i] = (float)(wr[i] * inv);
  }
  __syncthreads();
  // fp16 splat copies of the boundary tables (visible after the loop's first LBAR)
  if (tid < 6) {
    const int k = (tid < 3) ? tid : 250 + tid;   // 0,1,2,253,254,255
#pragma unroll
    for (int i = 0; i < 4; ++i) wUpH2[tid][i] = H2(wUpV[k][i]);
  }
  if (tid < 4) {
#pragma unroll
    for (int i = 0; i < 8; ++i) wDnH2[tid][i] = H2(wDnE[tid][i]);
  }

  const int bid = blockIdx.x;
  const int b = bid & 15;
  const int strip = (bid >> 4) & 7;
  const int chunk = bid >> 7;                  // 0..7
  const int oy0 = strip * RS;
  const int c0 = chunk * CH;
  const int c = tid & 15;                      // channel (lane-contiguous)
  const int g = tid >> 4;                      // col group 0..15
  const int col0 = g * 8;
  const bool gL = (g == 0), gR = (g == 15);

  const float* xbase = x + (size_t)b * (HH * WW * CC) + (size_t)col0 * CC + (c0 + c);
  float* obase = out + (size_t)b * (HH * WW * CC) + (size_t)col0 * CC + (c0 + c);
  const int m0 = oy0 - 2;

  auto ldrow = [&](float (&d)[8], int row) {
    row = row < 0 ? 0 : (row > 127 ? 127 : row);
    const float* p = xbase + (size_t)row * (WW * CC);
#pragma unroll
    for (int j = 0; j < 8; ++j) d[j] = p[j * CC];
  };

  // vertical-downsample weight for output row oy at tap (interior const cst)
  auto wdGet = [&](int oy, float cst, int tap) -> float {
    if (oy < 0 || oy > 127) return 0.f;
    if (oy < 2) return wDnE[oy][tap];
    if (oy > 125) return wDnE[oy - 124][tap];
    return cst;
  };

  // interior vertical-downsample weight pairs (dyadic /256 -> fp16-exact)
  const h2 WDA = (h2){(_Float16)(-0.01171875f), (_Float16)(0.f)};
  const h2 WDB = (h2){(_Float16)(0.11328125f), (_Float16)(-0.03515625f)};
  const h2 WDC = (h2){(_Float16)(0.43359375f), (_Float16)(0.43359375f)};
  const h2 WDD = (h2){(_Float16)(-0.03515625f), (_Float16)(0.11328125f)};
  const h2 WDE = (h2){(_Float16)(0.f), (_Float16)(-0.01171875f)};

  float R0[8], R1[8], R2[8], R3[8], R4[8];
  float A0[8], A1[8], A2[8], A3[8], A4[8];
#pragma unroll
  for (int i = 0; i < 8; ++i) { A0[i]=0.f; A1[i]=0.f; A2[i]=0.f; A3[i]=0.f; A4[i]=0.f; }

  ldrow(R0, m0 - 2);
  ldrow(R1, m0 - 1);
  ldrow(R2, m0);
  ldrow(R3, m0 + 1);
  ldrow(R4, m0 + 2);

// One coarse step at t=T_: ring (Ra..Re) = rows m-2..m+2; prefetches row m+3
// into Ra (vacated after the v-up); acc (Aa..Ae) = out rows m-2..m+2;
// stores+zeroes Aa.  Next step's names shift by one (period-5 renaming).
#define STEP(T_, Ra,Rb,Rc,Rd,Re, Aa,Ab,Ac,Ad,Ae) do {                          \
    const int m = m0 + (T_);                                                   \
    const bool mOK = (m >= 0) && (m <= 127);                                   \
    const int sp = (T_) & 1;                                                   \
    __align__(16) h2 vh[8];                                                    \
    if (mOK) {                                                                 \
      float4 we, wo;                                                           \
      if (m >= 2 && m <= 125) {                                                \
        we = make_float4(-0.0234375f, 0.2265625f, 0.8671875f, -0.0703125f);    \
        wo = make_float4(-0.0703125f, 0.8671875f, 0.2265625f, -0.0234375f);    \
      } else {                                                                 \
        we = *(const float4*)wUpV[2 * m];                                      \
        wo = *(const float4*)wUpV[2 * m + 1];                                  \
      }                                                                        \
      _Pragma("unroll") for (int j = 0; j < 8; ++j) {                          \
        const float vE = (we.x*Ra[j] + we.y*Rb[j]) + (we.z*Rc[j] + we.w*Rd[j]);\
        const float vO = (wo.x*Rb[j] + wo.y*Rc[j]) + (wo.z*Rd[j] + wo.w*Re[j]);\
        vh[j] = (h2){(_Float16)vE, (_Float16)vO};                              \
      }                                                                        \
      *(float4*)&rowv[sp][c][col0]     = *(const float4*)&vh[0];               \
      *(float4*)&rowv[sp][c][col0 + 4] = *(const float4*)&vh[4];               \
    }                                                                          \
    ldrow(Ra, m + 3);              /* prefetch into the vacated slot */        \
    LBAR();                                                                    \
    if (mOK) {                                                                 \
      __align__(16) h2 vv[16];                                                 \
      if (!gL) { *(float4*)&vv[0] = *(const float4*)&rowv[sp][c][col0 - 4]; }  \
      else { _Pragma("unroll") for (int i = 0; i < 4; ++i) vv[i] = H2(0.f); }  \
      _Pragma("unroll") for (int j = 0; j < 8; ++j) vv[4 + j] = vh[j];         \
      if (!gR) { *(float4*)&vv[12] = *(const float4*)&rowv[sp][c][col0 + 8]; } \
      else { _Pragma("unroll") for (int i = 0; i < 4; ++i) vv[12+i] = H2(0.f);}\
      h2 ff[22];                                                               \
      _Pragma("unroll") for (int u = 0; u < 22; ++u) {                         \
        const int s = (u >> 1) + 1;                                            \
        h2 t2;                                                                 \
        if (u & 1)                                                             \
          t2 = (vv[s] * H2(-0.0234375f) + vv[s + 1] * H2(0.2265625f))          \
             + (vv[s + 2] * H2(0.8671875f) + vv[s + 3] * H2(-0.0703125f));     \
        else                                                                   \
          t2 = (vv[s] * H2(-0.0703125f) + vv[s + 1] * H2(0.8671875f))          \
             + (vv[s + 2] * H2(0.2265625f) + vv[s + 3] * H2(-0.0234375f));     \
        ff[u] = __builtin_elementwise_max(t2, t2 * H2(0.01f));                 \
      }                                                                        \
      if (gL) {                                                                \
        _Pragma("unroll") for (int u = 3; u <= 5; ++u) {                       \
          const int s = (u >> 1) + 1;                                          \
          h2 t2 = (vv[s] * wUpH2[u-3][0] + vv[s+1] * wUpH2[u-3][1])            \
                + (vv[s+2] * wUpH2[u-3][2] + vv[s+3] * wUpH2[u-3][3]);         \
          ff[u] = __builtin_elementwise_max(t2, t2 * H2(0.01f));               \
        }                                                                      \
      }                                                                        \
      if (gR) {                                                                \
        _Pragma("unroll") for (int u = 16; u <= 18; ++u) {                     \
          const int s = (u >> 1) + 1;                                          \
          h2 t2 = (vv[s] * wUpH2[u-13][0] + vv[s+1] * wUpH2[u-13][1])          \
                + (vv[s+2] * wUpH2[u-13][2] + vv[s+3] * wUpH2[u-13][3]);       \
          ff[u] = __builtin_elementwise_max(t2, t2 * H2(0.01f));               \
        }                                                                      \
      }                                                                        \
      h2 tt[8];                                                                \
      _Pragma("unroll") for (int jj = 0; jj < 8; ++jj) {                       \
        const h2 p0 = ff[2*jj]     + ff[2*jj + 7];                             \
        const h2 p1 = ff[2*jj + 1] + ff[2*jj + 6];                             \
        const h2 p2 = ff[2*jj + 2] + ff[2*jj + 5];                             \
        const h2 p3 = ff[2*jj + 3] + ff[2*jj + 4];                             \
        tt[jj] = (p0 * H2(-0.01171875f) + p1 * H2(-0.03515625f))               \
               + (p2 * H2(0.11328125f)  + p3 * H2(0.43359375f));               \
      }                                                                        \
      if (gL) {                                                                \
        _Pragma("unroll") for (int jj = 0; jj < 2; ++jj) {                     \
          h2 s2 = H2(0.f);                                                     \
          _Pragma("unroll") for (int i = 0; i < 8; ++i)                        \
            s2 += ff[2*jj + i] * wDnH2[jj][i];                                 \
          tt[jj] = s2;                                                         \
        }                                                                      \
      }                                                                        \
      if (gR) {                                                                \
        _Pragma("unroll") for (int jj = 6; jj < 8; ++jj) {                     \
          h2 s2 = H2(0.f);                                                     \
          _Pragma("unroll") for (int i = 0; i < 8; ++i)                        \
            s2 += ff[2*jj + i] * wDnH2[jj - 4][i];                             \
          tt[jj] = s2;                                                         \
        }                                                                      \
      }                                                                        \
      if (m >= 4 && m <= 123) {      /* all affected out rows interior */      \
        _Pragma("unroll") for (int jj = 0; jj < 8; ++jj) {                     \
          Aa[jj] = __builtin_amdgcn_fdot2(tt[jj], WDA, Aa[jj], false);         \
          Ab[jj] = __builtin_amdgcn_fdot2(tt[jj], WDB, Ab[jj], false);         \
          Ac[jj] = __builtin_amdgcn_fdot2(tt[jj], WDC, Ac[jj], false);         \
          Ad[jj] = __builtin_amdgcn_fdot2(tt[jj], WDD, Ad[jj], false);         \
          Ae[jj] = __builtin_amdgcn_fdot2(tt[jj], WDE, Ae[jj], false);         \
        }                                                                      \
      } else {                       /* boundary: f32 path, table weights */   \
        const float wE0 = wdGet(m - 2, -0.01171875f, 7);                       \
        const float wE1 = wdGet(m - 1, 0.11328125f, 5);                        \
        const float wE2 = wdGet(m,     0.43359375f, 3);                        \
        const float wE3 = wdGet(m + 1, -0.03515625f, 1);                       \
        const float wO0 = wdGet(m - 1, -0.03515625f, 6);                       \
        const float wO1 = wdGet(m,     0.43359375f, 4);                        \
        const float wO2 = wdGet(m + 1, 0.11328125f, 2);                        \
        const float wO3 = wdGet(m + 2, -0.01171875f, 0);                       \
        _Pragma("unroll") for (int jj = 0; jj < 8; ++jj) {                     \
          const float te = (float)tt[jj].x, to = (float)tt[jj].y;              \
          Aa[jj] = fmaf(wE0, te, Aa[jj]);                                      \
          Ab[jj] = fmaf(wE1, te, fmaf(wO0, to, Ab[jj]));                       \
          Ac[jj] = fmaf(wE2, te, fmaf(wO1, to, Ac[jj]));                       \
          Ad[jj] = fmaf(wE3, te, fmaf(wO2, to, Ad[jj]));                       \
          Ae[jj] = fmaf(wO3, to, Ae[jj]);                                      \
        }                                                                      \
      }                                                                        \
    }                                                                          \
    if (m - 2 >= oy0) {                                                        \
      float* op = obase + (size_t)(m - 2) * (WW * CC);                         \
      _Pragma("unroll") for (int jj = 0; jj < 8; ++jj) op[jj * CC] = Aa[jj];   \
    }                                                                          \
    _Pragma("unroll") for (int jj = 0; jj < 8; ++jj) Aa[jj] = 0.f;             \
  } while (0)

  for (int tb = 0; tb < NSTEP; tb += 5) {
    STEP(tb + 0, R0,R1,R2,R3,R4, A0,A1,A2,A3,A4);
    STEP(tb + 1, R1,R2,R3,R4,R0, A1,A2,A3,A4,A0);
    STEP(tb + 2, R2,R3,R4,R0,R1, A2,A3,A4,A0,A1);
    STEP(tb + 3, R3,R4,R0,R1,R2, A3,A4,A0,A1,A2);
    STEP(tb + 4, R4,R0,R1,R2,R3, A4,A0,A1,A2,A3);
  }
#undef STEP
}

extern "C" void kernel_launch(void* const* d_in, const int* in_sizes, int n_in,
                              void* d_out, int out_size, void* d_ws, size_t ws_size,
                              hipStream_t stream) {
  const float* x = (const float*)d_in[0];
  float* o = (float*)d_out;
  dim3 grid(16 * 8 * 8);   // batch(16) x strips(8) x channel-chunks(8)
  dim3 block(256);
  hipLaunchKernelGGL(fused_updown_kernel, grid, block, 0, stream, x, o);
}

// Round 13
// 92.168 us; speedup vs baseline: 1.2267x; 1.0418x over previous
//
#include <hip/hip_runtime.h>

// Fused: bicubic 2x upsample -> leaky_relu(0.01) -> antialiased bicubic 2x down.
// NHWC f32, B=16, H=W=128, C=128.
// Round 13 = round 12 (fp16 packed horizontal pipeline, fdot2 v-down, renaming
// unroll, lgkm-only barrier) +
//  - PAIR processing: 2 coarse rows per barrier (10 barriers vs 20), 6-row
//    ring / 6 accumulators (period-3 pair renaming), 4 LDS slots
//  - PADH2 136: b128 LDS lane stride 68 dwords = 4 mod 32 -> 2 lanes/bank (free)
//  - first-touch overwrite of the last accumulator (no per-step zeroing)

typedef _Float16 h2 __attribute__((ext_vector_type(2)));

#define HH 128
#define WW 128
#define CC 128
#define RS 16       // output rows per strip
#define CH 16       // channels per block
#define PADH2 136   // LDS row stride in h2: 68 dwords/lane-step == 4 mod 32

// lgkm-only barrier: LDS visibility without draining global loads/stores.
#define LBAR() asm volatile("s_waitcnt lgkmcnt(0)\n\ts_barrier" ::: "memory")

__device__ __forceinline__ h2 H2(float v) {
  _Float16 h = (_Float16)v;
  return (h2){h, h};
}

__device__ __forceinline__ double keys_cubic(double x) {
  // JAX _fill_keys_cubic_kernel (a = -0.5)
  if (x >= 2.0) return 0.0;
  if (x >= 1.0) return ((-0.5 * x + 2.5) * x - 4.0) * x + 2.0;
  return (1.5 * x - 2.5) * x * x + 1.0;
}

__global__ __launch_bounds__(256) void fused_updown_kernel(
    const float* __restrict__ x, float* __restrict__ out) {
  __shared__ __align__(16) float wUpV[256][4];     // fine row -> 4 taps (f32, v-up)
  __shared__ __align__(16) float wDnE[4][8];       // out row/col 0,1,126,127 -> 8 taps
  __shared__ __align__(16) h2 wUpH2[6][4];         // fine col 0,1,2,253,254,255 (splat)
  __shared__ __align__(16) h2 wDnH2[4][8];         // out col 0,1,126,127 (splat)
  __shared__ __align__(16) h2 rowv[4][CH][PADH2];  // 4 slots: packed fine-row pairs

  const int tid = threadIdx.x;

  // ---- weight tables (renormalized truncation, matches jax.image.resize) ----
  {
    const int k = tid;
    const double q = 0.5 * k - 0.25;          // sample_f = (k+0.5)/2 - 0.5
    const int st = ((k + 1) >> 1) - 2;
    double wr[4], s = 0.0;
#pragma unroll
    for (int i = 0; i < 4; ++i) {
      const int col = st + i;
      double w = (col >= 0 && col <= 127) ? keys_cubic(fabs((double)col - q)) : 0.0;
      wr[i] = w; s += w;
    }
    const double inv = 1.0 / s;
#pragma unroll
    for (int i = 0; i < 4; ++i) wUpV[k][i] = (float)(wr[i] * inv);
  }
  if (tid < 4) {
    const int e = tid;
    const int j = (e < 2) ? e : 124 + e;      // 0,1,126,127
    const double p = 2.0 * j + 0.5;           // sample_f = (j+0.5)*2 - 0.5
    const int st = 2 * j - 3;
    double wr[8], s = 0.0;
#pragma unroll
    for (int i = 0; i < 8; ++i) {
      const int col = st + i;
      double w = (col >= 0 && col <= 255) ? keys_cubic(0.5 * fabs((double)col - p)) : 0.0;
      wr[i] = w; s += w;
    }
    const double inv = 1.0 / s;
#pragma unroll
    for (int i = 0; i < 8; ++i) wDnE[e][i] = (float)(wr[i] * inv);
  }
  __syncthreads();
  // fp16 splat copies of the boundary tables (visible after the first LBAR)
  if (tid < 6) {
    const int k = (tid < 3) ? tid : 250 + tid;   // 0,1,2,253,254,255
#pragma unroll
    for (int i = 0; i < 4; ++i) wUpH2[tid][i] = H2(wUpV[k][i]);
  }
  if (tid < 4) {
#pragma unroll
    for (int i = 0; i < 8; ++i) wDnH2[tid][i] = H2(wDnE[tid][i]);
  }

  const int bid = blockIdx.x;
  const int b = bid & 15;
  const int strip = (bid >> 4) & 7;
  const int chunk = bid >> 7;                  // 0..7
  const int oy0 = strip * RS;
  const int c0 = chunk * CH;
  const int c = tid & 15;                      // channel (lane-contiguous)
  const int g = tid >> 4;                      // col group 0..15
  const int col0 = g * 8;
  const bool gL = (g == 0), gR = (g == 15);

  const float* xbase = x + (size_t)b * (HH * WW * CC) + (size_t)col0 * CC + (c0 + c);
  float* obase = out + (size_t)b * (HH * WW * CC) + (size_t)col0 * CC + (c0 + c);
  const int m0 = oy0 - 2;

  auto ldrow = [&](float (&d)[8], int row) {
    row = row < 0 ? 0 : (row > 127 ? 127 : row);
    const float* p = xbase + (size_t)row * (WW * CC);
#pragma unroll
    for (int j = 0; j < 8; ++j) d[j] = p[j * CC];
  };

  // vertical-downsample weight for output row oy at tap (interior const cst)
  auto wdGet = [&](int oy, float cst, int tap) -> float {
    if (oy < 0 || oy > 127) return 0.f;
    if (oy < 2) return wDnE[oy][tap];
    if (oy > 125) return wDnE[oy - 124][tap];
    return cst;
  };

  // interior vertical-downsample weight pairs (dyadic /256 -> fp16-exact)
  const h2 WDA = (h2){(_Float16)(-0.01171875f), (_Float16)(0.f)};
  const h2 WDB = (h2){(_Float16)(0.11328125f), (_Float16)(-0.03515625f)};
  const h2 WDC = (h2){(_Float16)(0.43359375f), (_Float16)(0.43359375f)};
  const h2 WDD = (h2){(_Float16)(-0.03515625f), (_Float16)(0.11328125f)};
  const h2 WDE = (h2){(_Float16)(0.f), (_Float16)(-0.01171875f)};

// Horizontal pipeline for the packed fine-row pair of coarse row Mv, own
// values VH, halos in LDS slot SL.  P0..P3 accumulate; P4 is OVERWRITTEN
// (first touch of its out-row; skipped-overwrite cases covered by the
// startup zero-init since such registers are never stored).
#define PROCB(SL, Mv, VH, P0, P1, P2, P3, P4) do {                             \
    __align__(16) h2 vv[16];                                                   \
    if (!gL) { *(float4*)&vv[0] = *(const float4*)&rowv[SL][c][col0 - 4]; }    \
    else { _Pragma("unroll") for (int i = 0; i < 4; ++i) vv[i] = H2(0.f); }    \
    _Pragma("unroll") for (int j = 0; j < 8; ++j) vv[4 + j] = VH[j];           \
    if (!gR) { *(float4*)&vv[12] = *(const float4*)&rowv[SL][c][col0 + 8]; }   \
    else { _Pragma("unroll") for (int i = 0; i < 4; ++i) vv[12+i] = H2(0.f); } \
    h2 ff[22];                                                                 \
    _Pragma("unroll") for (int u = 0; u < 22; ++u) {                           \
      const int s = (u >> 1) + 1;                                              \
      h2 t2;                                                                   \
      if (u & 1)                                                               \
        t2 = (vv[s] * H2(-0.0234375f) + vv[s + 1] * H2(0.2265625f))            \
           + (vv[s + 2] * H2(0.8671875f) + vv[s + 3] * H2(-0.0703125f));       \
      else                                                                     \
        t2 = (vv[s] * H2(-0.0703125f) + vv[s + 1] * H2(0.8671875f))            \
           + (vv[s + 2] * H2(0.2265625f) + vv[s + 3] * H2(-0.0234375f));       \
      ff[u] = __builtin_elementwise_max(t2, t2 * H2(0.01f));                   \
    }                                                                          \
    if (gL) {                                                                  \
      _Pragma("unroll") for (int u = 3; u <= 5; ++u) {                         \
        const int s = (u >> 1) + 1;                                            \
        h2 t2 = (vv[s] * wUpH2[u-3][0] + vv[s+1] * wUpH2[u-3][1])              \
              + (vv[s+2] * wUpH2[u-3][2] + vv[s+3] * wUpH2[u-3][3]);           \
        ff[u] = __builtin_elementwise_max(t2, t2 * H2(0.01f));                 \
      }                                                                        \
    }                                                                          \
    if (gR) {                                                                  \
      _Pragma("unroll") for (int u = 16; u <= 18; ++u) {                       \
        const int s = (u >> 1) + 1;                                            \
        h2 t2 = (vv[s] * wUpH2[u-13][0] + vv[s+1] * wUpH2[u-13][1])            \
              + (vv[s+2] * wUpH2[u-13][2] + vv[s+3] * wUpH2[u-13][3]);         \
        ff[u] = __builtin_elementwise_max(t2, t2 * H2(0.01f));                 \
      }                                                                        \
    }                                                                          \
    h2 tt[8];                                                                  \
    _Pragma("unroll") for (int jj = 0; jj < 8; ++jj) {                         \
      const h2 q0 = ff[2*jj]     + ff[2*jj + 7];                               \
      const h2 q1 = ff[2*jj + 1] + ff[2*jj + 6];                               \
      const h2 q2 = ff[2*jj + 2] + ff[2*jj + 5];                               \
      const h2 q3 = ff[2*jj + 3] + ff[2*jj + 4];                               \
      tt[jj] = (q0 * H2(-0.01171875f) + q1 * H2(-0.03515625f))                 \
             + (q2 * H2(0.11328125f)  + q3 * H2(0.43359375f));                 \
    }                                                                          \
    if (gL) {                                                                  \
      _Pragma("unroll") for (int jj = 0; jj < 2; ++jj) {                       \
        h2 s2 = H2(0.f);                                                       \
        _Pragma("unroll") for (int i = 0; i < 8; ++i)                          \
          s2 += ff[2*jj + i] * wDnH2[jj][i];                                   \
        tt[jj] = s2;                                                           \
      }                                                                        \
    }                                                                          \
    if (gR) {                                                                  \
      _Pragma("unroll") for (int jj = 6; jj < 8; ++jj) {                       \
        h2 s2 = H2(0.f);                                                       \
        _Pragma("unroll") for (int i = 0; i < 8; ++i)                          \
          s2 += ff[2*jj + i] * wDnH2[jj - 4][i];                               \
        tt[jj] = s2;                                                           \
      }                                                                        \
    }                                                                          \
    if ((Mv) >= 4 && (Mv) <= 123) {                                            \
      _Pragma("unroll") for (int jj = 0; jj < 8; ++jj) {                       \
        P0[jj] = __builtin_amdgcn_fdot2(tt[jj], WDA, P0[jj], false);           \
        P1[jj] = __builtin_amdgcn_fdot2(tt[jj], WDB, P1[jj], false);           \
        P2[jj] = __builtin_amdgcn_fdot2(tt[jj], WDC, P2[jj], false);           \
        P3[jj] = __builtin_amdgcn_fdot2(tt[jj], WDD, P3[jj], false);           \
        P4[jj] = __builtin_amdgcn_fdot2(tt[jj], WDE, 0.f, false);              \
      }                                                                        \
    } else {                                                                   \
      const float wE0 = wdGet((Mv) - 2, -0.01171875f, 7);                      \
      const float wE1 = wdGet((Mv) - 1, 0.11328125f, 5);                       \
      const float wE2 = wdGet((Mv),     0.43359375f, 3);                       \
      const float wE3 = wdGet((Mv) + 1, -0.03515625f, 1);                      \
      const float wO0 = wdGet((Mv) - 1, -0.03515625f, 6);                      \
      const float wO1 = wdGet((Mv),     0.43359375f, 4);                       \
      const float wO2 = wdGet((Mv) + 1, 0.11328125f, 2);                       \
      const float wO3 = wdGet((Mv) + 2, -0.01171875f, 0);                      \
      _Pragma("unroll") for (int jj = 0; jj < 8; ++jj) {                       \
        const float te = (float)tt[jj].x, to = (float)tt[jj].y;                \
        P0[jj] = fmaf(wE0, te, P0[jj]);                                        \
        P1[jj] = fmaf(wE1, te, fmaf(wO0, to, P1[jj]));                         \
        P2[jj] = fmaf(wE2, te, fmaf(wO1, to, P2[jj]));                         \
        P3[jj] = fmaf(wE3, te, fmaf(wO2, to, P3[jj]));                         \
        P4[jj] = wO3 * to;                                                     \
      }                                                                        \
    }                                                                          \
  } while (0)

// One pair: coarse rows mA=m0+2P, mB=mA+1 (mA always even -> pair uniformly
// valid or invalid).  Ring Ra..Rf = rows mA-2..mA+3 at entry; prefetches
// rows mA+4,mA+5 into the vacated Ra,Rb.  Accs Aa..Af = out rows mA-2..mA+3;
// stores Aa,Ab.  One barrier per pair; slots 2(P&1),2(P&1)+1 (reuse distance
// 2 pairs with an intervening barrier).
#define PAIR(P_, Ra,Rb,Rc,Rd,Re,Rf, Aa,Ab,Ac,Ad,Ae,Af) do {                    \
    const int mA = m0 + 2 * (P_);                                              \
    const int mB = mA + 1;                                                     \
    const bool pOK = (mA >= 0) && (mB <= 127);                                 \
    const int sA = ((P_) & 1) * 2;                                             \
    __align__(16) h2 vhA[8], vhB[8];                                           \
    if (pOK) {                                                                 \
      float4 weA, woA, weB, woB;                                               \
      if (mA >= 2 && mA <= 125) {                                              \
        weA = make_float4(-0.0234375f, 0.2265625f, 0.8671875f, -0.0703125f);   \
        woA = make_float4(-0.0703125f, 0.8671875f, 0.2265625f, -0.0234375f);   \
      } else {                                                                 \
        weA = *(const float4*)wUpV[2 * mA];                                    \
        woA = *(const float4*)wUpV[2 * mA + 1];                                \
      }                                                                        \
      if (mB >= 2 && mB <= 125) {                                              \
        weB = make_float4(-0.0234375f, 0.2265625f, 0.8671875f, -0.0703125f);   \
        woB = make_float4(-0.0703125f, 0.8671875f, 0.2265625f, -0.0234375f);   \
      } else {                                                                 \
        weB = *(const float4*)wUpV[2 * mB];                                    \
        woB = *(const float4*)wUpV[2 * mB + 1];                                \
      }                                                                        \
      _Pragma("unroll") for (int j = 0; j < 8; ++j) {                          \
        const float vEA = (weA.x*Ra[j] + weA.y*Rb[j])                          \
                        + (weA.z*Rc[j] + weA.w*Rd[j]);                         \
        const float vOA = (woA.x*Rb[j] + woA.y*Rc[j])                          \
                        + (woA.z*Rd[j] + woA.w*Re[j]);                         \
        vhA[j] = (h2){(_Float16)vEA, (_Float16)vOA};                           \
        const float vEB = (weB.x*Rb[j] + weB.y*Rc[j])                          \
                        + (weB.z*Rd[j] + weB.w*Re[j]);                         \
        const float vOB = (woB.x*Rc[j] + woB.y*Rd[j])                          \
                        + (woB.z*Re[j] + woB.w*Rf[j]);                         \
        vhB[j] = (h2){(_Float16)vEB, (_Float16)vOB};                           \
      }                                                                        \
      *(float4*)&rowv[sA][c][col0]         = *(const float4*)&vhA[0];          \
      *(float4*)&rowv[sA][c][col0 + 4]     = *(const float4*)&vhA[4];          \
      *(float4*)&rowv[sA + 1][c][col0]     = *(const float4*)&vhB[0];          \
      *(float4*)&rowv[sA + 1][c][col0 + 4] = *(const float4*)&vhB[4];          \
    }                                                                          \
    ldrow(Ra, mA + 4);                                                         \
    ldrow(Rb, mA + 5);                                                         \
    LBAR();                                                                    \
    if (pOK) {                                                                 \
      PROCB(sA,     mA, vhA, Aa, Ab, Ac, Ad, Ae);                              \
      PROCB(sA + 1, mB, vhB, Ab, Ac, Ad, Ae, Af);                              \
    }                                                                          \
    if (mA - 2 >= oy0) {                                                       \
      float* op = obase + (size_t)(mA - 2) * (WW * CC);                        \
      _Pragma("unroll") for (int jj = 0; jj < 8; ++jj) op[jj * CC] = Aa[jj];   \
    }                                                                          \
    if (mB - 2 >= oy0) {                                                       \
      float* op = obase + (size_t)(mB - 2) * (WW * CC);                        \
      _Pragma("unroll") for (int jj = 0; jj < 8; ++jj) op[jj * CC] = Ab[jj];   \
    }                                                                          \
  } while (0)

  float R0[8], R1[8], R2[8], R3[8], R4[8], R5[8];
  float A0[8], A1[8], A2[8], A3[8], A4[8], A5[8];
#pragma unroll
  for (int i = 0; i < 8; ++i) {
    A0[i]=0.f; A1[i]=0.f; A2[i]=0.f; A3[i]=0.f; A4[i]=0.f; A5[i]=0.f;
  }
  ldrow(R0, m0 - 2);
  ldrow(R1, m0 - 1);
  ldrow(R2, m0);
  ldrow(R3, m0 + 1);
  ldrow(R4, m0 + 2);
  ldrow(R5, m0 + 3);

  for (int i = 0; i < 3; ++i) {
    const int p = 3 * i;
    PAIR(p,     R0,R1,R2,R3,R4,R5, A0,A1,A2,A3,A4,A5);
    PAIR(p + 1, R2,R3,R4,R5,R0,R1, A2,A3,A4,A5,A0,A1);
    PAIR(p + 2, R4,R5,R0,R1,R2,R3, A4,A5,A0,A1,A2,A3);
  }
  PAIR(9, R0,R1,R2,R3,R4,R5, A0,A1,A2,A3,A4,A5);

#undef PAIR
#undef PROCB
}

extern "C" void kernel_launch(void* const* d_in, const int* in_sizes, int n_in,
                              void* d_out, int out_size, void* d_ws, size_t ws_size,
                              hipStream_t stream) {
  const float* x = (const float*)d_in[0];
  float* o = (float*)d_out;
  dim3 grid(16 * 8 * 8);   // batch(16) x strips(8) x channel-chunks(8)
  dim3 block(256);
  hipLaunchKernelGGL(fused_updown_kernel, grid, block, 0, stream, x, o);
}

// Round 14
// 90.792 us; speedup vs baseline: 1.2453x; 1.0152x over previous
//
#include <hip/hip_runtime.h>

// Fused: bicubic 2x upsample -> leaky_relu(0.01) -> antialiased bicubic 2x down.
// NHWC f32, B=16, H=W=128, C=128.
// Round 14 = round 13 with PADH2 reverted 136->132.  Bank math: stride per
// channel = PADH2 dwords; 132 == 4 (mod 32) -> adjacent lanes' b128 windows
// tile 32 banks at the structural 2-lanes/bank minimum; 136 == 8 (mod 32)
// piled 4 lanes/bank (r13: conflicts 1.88M -> 4.95M).  528B row stride keeps
// 16B alignment for b128.

typedef _Float16 h2 __attribute__((ext_vector_type(2)));

#define HH 128
#define WW 128
#define CC 128
#define RS 16       // output rows per strip
#define CH 16       // channels per block
#define PADH2 132   // LDS row stride in h2: 132 dwords/channel == 4 mod 32

// lgkm-only barrier: LDS visibility without draining global loads/stores.
#define LBAR() asm volatile("s_waitcnt lgkmcnt(0)\n\ts_barrier" ::: "memory")

__device__ __forceinline__ h2 H2(float v) {
  _Float16 h = (_Float16)v;
  return (h2){h, h};
}

__device__ __forceinline__ double keys_cubic(double x) {
  // JAX _fill_keys_cubic_kernel (a = -0.5)
  if (x >= 2.0) return 0.0;
  if (x >= 1.0) return ((-0.5 * x + 2.5) * x - 4.0) * x + 2.0;
  return (1.5 * x - 2.5) * x * x + 1.0;
}

__global__ __launch_bounds__(256) void fused_updown_kernel(
    const float* __restrict__ x, float* __restrict__ out) {
  __shared__ __align__(16) float wUpV[256][4];     // fine row -> 4 taps (f32, v-up)
  __shared__ __align__(16) float wDnE[4][8];       // out row/col 0,1,126,127 -> 8 taps
  __shared__ __align__(16) h2 wUpH2[6][4];         // fine col 0,1,2,253,254,255 (splat)
  __shared__ __align__(16) h2 wDnH2[4][8];         // out col 0,1,126,127 (splat)
  __shared__ __align__(16) h2 rowv[4][CH][PADH2];  // 4 slots: packed fine-row pairs

  const int tid = threadIdx.x;

  // ---- weight tables (renormalized truncation, matches jax.image.resize) ----
  {
    const int k = tid;
    const double q = 0.5 * k - 0.25;          // sample_f = (k+0.5)/2 - 0.5
    const int st = ((k + 1) >> 1) - 2;
    double wr[4], s = 0.0;
#pragma unroll
    for (int i = 0; i < 4; ++i) {
      const int col = st + i;
      double w = (col >= 0 && col <= 127) ? keys_cubic(fabs((double)col - q)) : 0.0;
      wr[i] = w; s += w;
    }
    const double inv = 1.0 / s;
#pragma unroll
    for (int i = 0; i < 4; ++i) wUpV[k][i] = (float)(wr[i] * inv);
  }
  if (tid < 4) {
    const int e = tid;
    const int j = (e < 2) ? e : 124 + e;      // 0,1,126,127
    const double p = 2.0 * j + 0.5;           // sample_f = (j+0.5)*2 - 0.5
    const int st = 2 * j - 3;
    double wr[8], s = 0.0;
#pragma unroll
    for (int i = 0; i < 8; ++i) {
      const int col = st + i;
      double w = (col >= 0 && col <= 255) ? keys_cubic(0.5 * fabs((double)col - p)) : 0.0;
      wr[i] = w; s += w;
    }
    const double inv = 1.0 / s;
#pragma unroll
    for (int i = 0; i < 8; ++i) wDnE[e][i] = (float)(wr[i] * inv);
  }
  __syncthreads();
  // fp16 splat copies of the boundary tables (visible after the first LBAR)
  if (tid < 6) {
    const int k = (tid < 3) ? tid : 250 + tid;   // 0,1,2,253,254,255
#pragma unroll
    for (int i = 0; i < 4; ++i) wUpH2[tid][i] = H2(wUpV[k][i]);
  }
  if (tid < 4) {
#pragma unroll
    for (int i = 0; i < 8; ++i) wDnH2[tid][i] = H2(wDnE[tid][i]);
  }

  const int bid = blockIdx.x;
  const int b = bid & 15;
  const int strip = (bid >> 4) & 7;
  const int chunk = bid >> 7;                  // 0..7
  const int oy0 = strip * RS;
  const int c0 = chunk * CH;
  const int c = tid & 15;                      // channel (lane-contiguous)
  const int g = tid >> 4;                      // col group 0..15
  const int col0 = g * 8;
  const bool gL = (g == 0), gR = (g == 15);

  const float* xbase = x + (size_t)b * (HH * WW * CC) + (size_t)col0 * CC + (c0 + c);
  float* obase = out + (size_t)b * (HH * WW * CC) + (size_t)col0 * CC + (c0 + c);
  const int m0 = oy0 - 2;

  auto ldrow = [&](float (&d)[8], int row) {
    row = row < 0 ? 0 : (row > 127 ? 127 : row);
    const float* p = xbase + (size_t)row * (WW * CC);
#pragma unroll
    for (int j = 0; j < 8; ++j) d[j] = p[j * CC];
  };

  // vertical-downsample weight for output row oy at tap (interior const cst)
  auto wdGet = [&](int oy, float cst, int tap) -> float {
    if (oy < 0 || oy > 127) return 0.f;
    if (oy < 2) return wDnE[oy][tap];
    if (oy > 125) return wDnE[oy - 124][tap];
    return cst;
  };

  // interior vertical-downsample weight pairs (dyadic /256 -> fp16-exact)
  const h2 WDA = (h2){(_Float16)(-0.01171875f), (_Float16)(0.f)};
  const h2 WDB = (h2){(_Float16)(0.11328125f), (_Float16)(-0.03515625f)};
  const h2 WDC = (h2){(_Float16)(0.43359375f), (_Float16)(0.43359375f)};
  const h2 WDD = (h2){(_Float16)(-0.03515625f), (_Float16)(0.11328125f)};
  const h2 WDE = (h2){(_Float16)(0.f), (_Float16)(-0.01171875f)};

// Horizontal pipeline for the packed fine-row pair of coarse row Mv, own
// values VH, halos in LDS slot SL.  P0..P3 accumulate; P4 is OVERWRITTEN
// (first touch of its out-row; skipped-overwrite cases covered by the
// startup zero-init since such registers are never stored).
#define PROCB(SL, Mv, VH, P0, P1, P2, P3, P4) do {                             \
    __align__(16) h2 vv[16];                                                   \
    if (!gL) { *(float4*)&vv[0] = *(const float4*)&rowv[SL][c][col0 - 4]; }    \
    else { _Pragma("unroll") for (int i = 0; i < 4; ++i) vv[i] = H2(0.f); }    \
    _Pragma("unroll") for (int j = 0; j < 8; ++j) vv[4 + j] = VH[j];           \
    if (!gR) { *(float4*)&vv[12] = *(const float4*)&rowv[SL][c][col0 + 8]; }   \
    else { _Pragma("unroll") for (int i = 0; i < 4; ++i) vv[12+i] = H2(0.f); } \
    h2 ff[22];                                                                 \
    _Pragma("unroll") for (int u = 0; u < 22; ++u) {                           \
      const int s = (u >> 1) + 1;                                              \
      h2 t2;                                                                   \
      if (u & 1)                                                               \
        t2 = (vv[s] * H2(-0.0234375f) + vv[s + 1] * H2(0.2265625f))            \
           + (vv[s + 2] * H2(0.8671875f) + vv[s + 3] * H2(-0.0703125f));       \
      else                                                                     \
        t2 = (vv[s] * H2(-0.0703125f) + vv[s + 1] * H2(0.8671875f))            \
           + (vv[s + 2] * H2(0.2265625f) + vv[s + 3] * H2(-0.0234375f));       \
      ff[u] = __builtin_elementwise_max(t2, t2 * H2(0.01f));                   \
    }                                                                          \
    if (gL) {                                                                  \
      _Pragma("unroll") for (int u = 3; u <= 5; ++u) {                         \
        const int s = (u >> 1) + 1;                                            \
        h2 t2 = (vv[s] * wUpH2[u-3][0] + vv[s+1] * wUpH2[u-3][1])              \
              + (vv[s+2] * wUpH2[u-3][2] + vv[s+3] * wUpH2[u-3][3]);           \
        ff[u] = __builtin_elementwise_max(t2, t2 * H2(0.01f));                 \
      }                                                                        \
    }                                                                          \
    if (gR) {                                                                  \
      _Pragma("unroll") for (int u = 16; u <= 18; ++u) {                       \
        const int s = (u >> 1) + 1;                                            \
        h2 t2 = (vv[s] * wUpH2[u-13][0] + vv[s+1] * wUpH2[u-13][1])            \
              + (vv[s+2] * wUpH2[u-13][2] + vv[s+3] * wUpH2[u-13][3]);         \
        ff[u] = __builtin_elementwise_max(t2, t2 * H2(0.01f));                 \
      }                                                                        \
    }                                                                          \
    h2 tt[8];                                                                  \
    _Pragma("unroll") for (int jj = 0; jj < 8; ++jj) {                         \
      const h2 q0 = ff[2*jj]     + ff[2*jj + 7];                               \
      const h2 q1 = ff[2*jj + 1] + ff[2*jj + 6];                               \
      const h2 q2 = ff[2*jj + 2] + ff[2*jj + 5];                               \
      const h2 q3 = ff[2*jj + 3] + ff[2*jj + 4];                               \
      tt[jj] = (q0 * H2(-0.01171875f) + q1 * H2(-0.03515625f))                 \
             + (q2 * H2(0.11328125f)  + q3 * H2(0.43359375f));                 \
    }                                                                          \
    if (gL) {                                                                  \
      _Pragma("unroll") for (int jj = 0; jj < 2; ++jj) {                       \
        h2 s2 = H2(0.f);                                                       \
        _Pragma("unroll") for (int i = 0; i < 8; ++i)                          \
          s2 += ff[2*jj + i] * wDnH2[jj][i];                                   \
        tt[jj] = s2;                                                           \
      }                                                                        \
    }                                                                          \
    if (gR) {                                                                  \
      _Pragma("unroll") for (int jj = 6; jj < 8; ++jj) {                       \
        h2 s2 = H2(0.f);                                                       \
        _Pragma("unroll") for (int i = 0; i < 8; ++i)                          \
          s2 += ff[2*jj + i] * wDnH2[jj - 4][i];                               \
        tt[jj] = s2;                                                           \
      }                                                                        \
    }                                                                          \
    if ((Mv) >= 4 && (Mv) <= 123) {                                            \
      _Pragma("unroll") for (int jj = 0; jj < 8; ++jj) {                       \
        P0[jj] = __builtin_amdgcn_fdot2(tt[jj], WDA, P0[jj], false);           \
        P1[jj] = __builtin_amdgcn_fdot2(tt[jj], WDB, P1[jj], false);           \
        P2[jj] = __builtin_amdgcn_fdot2(tt[jj], WDC, P2[jj], false);           \
        P3[jj] = __builtin_amdgcn_fdot2(tt[jj], WDD, P3[jj], false);           \
        P4[jj] = __builtin_amdgcn_fdot2(tt[jj], WDE, 0.f, false);              \
      }                                                                        \
    } else {                                                                   \
      const float wE0 = wdGet((Mv) - 2, -0.01171875f, 7);                      \
      const float wE1 = wdGet((Mv) - 1, 0.11328125f, 5);                       \
      const float wE2 = wdGet((Mv),     0.43359375f, 3);                       \
      const float wE3 = wdGet((Mv) + 1, -0.03515625f, 1);                      \
      const float wO0 = wdGet((Mv) - 1, -0.03515625f, 6);                      \
      const float wO1 = wdGet((Mv),     0.43359375f, 4);                       \
      const float wO2 = wdGet((Mv) + 1, 0.11328125f, 2);                       \
      const float wO3 = wdGet((Mv) + 2, -0.01171875f, 0);                      \
      _Pragma("unroll") for (int jj = 0; jj < 8; ++jj) {                       \
        const float te = (float)tt[jj].x, to = (float)tt[jj].y;                \
        P0[jj] = fmaf(wE0, te, P0[jj]);                                        \
        P1[jj] = fmaf(wE1, te, fmaf(wO0, to, P1[jj]));                         \
        P2[jj] = fmaf(wE2, te, fmaf(wO1, to, P2[jj]));                         \
        P3[jj] = fmaf(wE3, te, fmaf(wO2, to, P3[jj]));                         \
        P4[jj] = wO3 * to;                                                     \
      }                                                                        \
    }                                                                          \
  } while (0)

// One pair: coarse rows mA=m0+2P, mB=mA+1 (mA always even -> pair uniformly
// valid or invalid).  Ring Ra..Rf = rows mA-2..mA+3 at entry; prefetches
// rows mA+4,mA+5 into the vacated Ra,Rb.  Accs Aa..Af = out rows mA-2..mA+3;
// stores Aa,Ab.  One barrier per pair; slots 2(P&1),2(P&1)+1 (reuse distance
// 2 pairs with an intervening barrier).
#define PAIR(P_, Ra,Rb,Rc,Rd,Re,Rf, Aa,Ab,Ac,Ad,Ae,Af) do {                    \
    const int mA = m0 + 2 * (P_);                                              \
    const int mB = mA + 1;                                                     \
    const bool pOK = (mA >= 0) && (mB <= 127);                                 \
    const int sA = ((P_) & 1) * 2;                                             \
    __align__(16) h2 vhA[8], vhB[8];                                           \
    if (pOK) {                                                                 \
      float4 weA, woA, weB, woB;                                               \
      if (mA >= 2 && mA <= 125) {                                              \
        weA = make_float4(-0.0234375f, 0.2265625f, 0.8671875f, -0.0703125f);   \
        woA = make_float4(-0.0703125f, 0.8671875f, 0.2265625f, -0.0234375f);   \
      } else {                                                                 \
        weA = *(const float4*)wUpV[2 * mA];                                    \
        woA = *(const float4*)wUpV[2 * mA + 1];                                \
      }                                                                        \
      if (mB >= 2 && mB <= 125) {                                              \
        weB = make_float4(-0.0234375f, 0.2265625f, 0.8671875f, -0.0703125f);   \
        woB = make_float4(-0.0703125f, 0.8671875f, 0.2265625f, -0.0234375f);   \
      } else {                                                                 \
        weB = *(const float4*)wUpV[2 * mB];                                    \
        woB = *(const float4*)wUpV[2 * mB + 1];                                \
      }                                                                        \
      _Pragma("unroll") for (int j = 0; j < 8; ++j) {                          \
        const float vEA = (weA.x*Ra[j] + weA.y*Rb[j])                          \
                        + (weA.z*Rc[j] + weA.w*Rd[j]);                         \
        const float vOA = (woA.x*Rb[j] + woA.y*Rc[j])                          \
                        + (woA.z*Rd[j] + woA.w*Re[j]);                         \
        vhA[j] = (h2){(_Float16)vEA, (_Float16)vOA};                           \
        const float vEB = (weB.x*Rb[j] + weB.y*Rc[j])                          \
                        + (weB.z*Rd[j] + weB.w*Re[j]);                         \
        const float vOB = (woB.x*Rc[j] + woB.y*Rd[j])                          \
                        + (woB.z*Re[j] + woB.w*Rf[j]);                         \
        vhB[j] = (h2){(_Float16)vEB, (_Float16)vOB};                           \
      }                                                                        \
      *(float4*)&rowv[sA][c][col0]         = *(const float4*)&vhA[0];          \
      *(float4*)&rowv[sA][c][col0 + 4]     = *(const float4*)&vhA[4];          \
      *(float4*)&rowv[sA + 1][c][col0]     = *(const float4*)&vhB[0];          \
      *(float4*)&rowv[sA + 1][c][col0 + 4] = *(const float4*)&vhB[4];          \
    }                                                                          \
    ldrow(Ra, mA + 4);                                                         \
    ldrow(Rb, mA + 5);                                                         \
    LBAR();                                                                    \
    if (pOK) {                                                                 \
      PROCB(sA,     mA, vhA, Aa, Ab, Ac, Ad, Ae);                              \
      PROCB(sA + 1, mB, vhB, Ab, Ac, Ad, Ae, Af);                              \
    }                                                                          \
    if (mA - 2 >= oy0) {                                                       \
      float* op = obase + (size_t)(mA - 2) * (WW * CC);                        \
      _Pragma("unroll") for (int jj = 0; jj < 8; ++jj) op[jj * CC] = Aa[jj];   \
    }                                                                          \
    if (mB - 2 >= oy0) {                                                       \
      float* op = obase + (size_t)(mB - 2) * (WW * CC);                        \
      _Pragma("unroll") for (int jj = 0; jj < 8; ++jj) op[jj * CC] = Ab[jj];   \
    }                                                                          \
  } while (0)

  float R0[8], R1[8], R2[8], R3[8], R4[8], R5[8];
  float A0[8], A1[8], A2[8], A3[8], A4[8], A5[8];
#pragma unroll
  for (int i = 0; i < 8; ++i) {
    A0[i]=0.f; A1[i]=0.f; A2[i]=0.f; A3[i]=0.f; A4[i]=0.f; A5[i]=0.f;
  }
  ldrow(R0, m0 - 2);
  ldrow(R1, m0 - 1);
  ldrow(R2, m0);
  ldrow(R3, m0 + 1);
  ldrow(R4, m0 + 2);
  ldrow(R5, m0 + 3);

  for (int i = 0; i < 3; ++i) {
    const int p = 3 * i;
    PAIR(p,     R0,R1,R2,R3,R4,R5, A0,A1,A2,A3,A4,A5);
    PAIR(p + 1, R2,R3,R4,R5,R0,R1, A2,A3,A4,A5,A0,A1);
    PAIR(p + 2, R4,R5,R0,R1,R2,R3, A4,A5,A0,A1,A2,A3);
  }
  PAIR(9, R0,R1,R2,R3,R4,R5, A0,A1,A2,A3,A4,A5);

#undef PAIR
#undef PROCB
}

extern "C" void kernel_launch(void* const* d_in, const int* in_sizes, int n_in,
                              void* d_out, int out_size, void* d_ws, size_t ws_size,
                              hipStream_t stream) {
  const float* x = (const float*)d_in[0];
  float* o = (float*)d_out;
  dim3 grid(16 * 8 * 8);   // batch(16) x strips(8) x channel-chunks(8)
  dim3 block(256);
  hipLaunchKernelGGL(fused_updown_kernel, grid, block, 0, stream, x, o);
}